// Round 16
// baseline (163.119 us; speedup 1.0000x reference)
//
#include <hip/hip_runtime.h>
#include <math.h>

// Chamfer distance, B=4, H=W=128, HW=16384, threshold 0.1.
// ws layout:
//   [0,128)   int segcounts[8][4]   (plain stores, no memset needed)
//   [256, 256+8*HW*16)   float4 pts[8][HW]   segmented semi-dense:
//                        combo's seg s actives at [s*4096, s*4096+cnt)
//   [+2MB, +2MB+8*HW*4)  uint  minarr[8][HW] (d^2 bits, slot-indexed, atomicMin)

#define B_ 4
#define HW_ 16384
#define THRESH 0.1f
#define BIGF 1e30f
#define EPS_ 1e-12f

#define NTHR 512       // dist: 8 waves/block
#define RROWS 16       // rows/thread: keeps ds_read_b128 issue under VALU demand
#define NCHUNK 128     // to-split: 128 x 8 combos = 1024 blocks = 4/CU, 32 waves/CU
#define MAXCHUNK 128   // ceil(HW/NCHUNK)
#define SEGCAP 4096    // elements per compaction segment
#define NSEG 4

// Atomic-free compaction: one block per (segment, combo). 1024 thr x 4 elems,
// float4 loads; in-block prefix scan (wave shfl + LDS); actives written dense
// within the segment; per-seg count = plain store. minarr init via uint4.
__global__ __launch_bounds__(1024)
void compact_kernel(const float* __restrict__ in1, const float* __restrict__ in2,
                    int* __restrict__ segcounts, float4* __restrict__ pts,
                    uint4* __restrict__ minarr4) {
    int seg = blockIdx.x, combo = blockIdx.y;
    int b = combo >> 1, s = combo & 1;
    int tid = threadIdx.x, lane = tid & 63, wid = tid >> 6;
    const float* in = s ? in2 : in1;
    int ibase = seg * SEGCAP + tid * 4;              // element index in image
    float4 v = ((const float4*)(in + b * HW_))[(unsigned)ibase >> 2];
    float w0 = v.x - THRESH, w1 = v.y - THRESH, w2 = v.z - THRESH, w3 = v.w - THRESH;
    int a0 = w0 > 0.f, a1 = w1 > 0.f, a2 = w2 > 0.f, a3 = w3 > 0.f;

    unsigned int bb = __float_as_uint(BIGF);
    minarr4[(unsigned)(combo * HW_ + ibase) >> 2] = make_uint4(bb, bb, bb, bb);

    int c = a0 + a1 + a2 + a3;
    int incl = c;
#pragma unroll
    for (int o = 1; o < 64; o <<= 1) {
        int x = __shfl_up(incl, o, 64);
        if (lane >= o) incl += x;
    }
    int wexcl = incl - c;
    __shared__ int wtot[16], wpre[17];
    if (lane == 63) wtot[wid] = incl;
    __syncthreads();
    if (tid == 0) {
        int run = 0;
#pragma unroll
        for (int ww = 0; ww < 16; ++ww) { wpre[ww] = run; run += wtot[ww]; }
        wpre[16] = run;
    }
    __syncthreads();
    int off = wpre[wid] + wexcl;
    float4* dst = pts + combo * HW_ + seg * SEGCAP;
    float wv[4] = {w0, w1, w2, w3};
    int   av[4] = {a0, a1, a2, a3};
#pragma unroll
    for (int u = 0; u < 4; ++u) {
        if (av[u]) {
            int i = ibase + u;
            float qx = (float)(i >> 7) * wv[u];
            float qy = (float)(i & 127) * wv[u];
            dst[off] = make_float4(qx, qy, qx * qx + qy * qy, 0.0f);
            ++off;
        }
    }
    if (tid == 0) segcounts[combo * 4 + seg] = wpre[16];
}

// dense index r in [0, n) -> segmented slot, given prefix offsets o1<=o2<=o3.
__device__ __forceinline__ int map_slot(int r, int o1, int o2, int o3) {
    int slot = r;
    slot = (r >= o1) ? r - o1 + SEGCAP     : slot;
    slot = (r >= o2) ? r - o2 + 2 * SEGCAP : slot;
    slot = (r >= o3) ? r - o3 + 3 * SEGCAP : slot;
    return slot;
}

// grid (NCHUNK, 8 combos), 512 threads, 4 blocks/CU (32 waves = full occupancy).
// Stage this block's to-chunk (<=128 float4 = 2KB, padded to x4 with BIG
// sentinels) into LDS once; each thread min-reduces RROWS=16 rows against it
// (dot form: 2 FMA + 0.5 min3 per pair, quad-unrolled, no remainder loop).
// Cross-chunk combine via uint atomicMin on d^2 bits (>=0 -> uint order ok).
__global__ __launch_bounds__(NTHR, 8)   // 8 waves/EU: VGPR cap 64 (now 60)
void dist_kernel(const int* __restrict__ segcounts,
                 const float4* __restrict__ pts,
                 unsigned int* __restrict__ minarr) {
    int chunk = blockIdx.x;
    int combo = blockIdx.y;
    int tid = threadIdx.x;
    int tc = combo ^ 1;
    int f1 = segcounts[combo * 4];
    int f2 = f1 + segcounts[combo * 4 + 1];
    int f3 = f2 + segcounts[combo * 4 + 2];
    int n_from = f3 + segcounts[combo * 4 + 3];
    int t1 = segcounts[tc * 4];
    int t2 = t1 + segcounts[tc * 4 + 1];
    int t3 = t2 + segcounts[tc * 4 + 2];
    int n_to = t3 + segcounts[tc * 4 + 3];
    if (n_from <= 0 || n_to <= 0) return;

    int len   = (n_to + NCHUNK - 1) / NCHUNK;
    int start = chunk * len;
    int end   = min(start + len, n_to);
    int clen  = end - start;
    if (clen <= 0) return;                       // block-uniform, before any sync
    int cpad  = (clen + 3) & ~3;                 // <= MAXCHUNK always

    const float4* __restrict__ to   = pts + tc * HW_;
    const float4* __restrict__ from = pts + combo * HW_;

    __shared__ float4 buf[MAXCHUNK];
    if (tid < clen)
        buf[tid] = to[map_slot(start + tid, t1, t2, t3)];
    else if (tid < cpad)
        buf[tid] = make_float4(0.0f, 0.0f, BIGF, 0.0f);  // sentinel: never the min
    __syncthreads();

    for (int rbase = 0; rbase < n_from; rbase += NTHR * RROWS) {
        int rd[RROWS], slot[RROWS];
        float n2px[RROWS], n2py[RROWS], p2[RROWS], m[RROWS];
#pragma unroll
        for (int k = 0; k < RROWS; ++k) {
            rd[k] = rbase + tid + k * NTHR;
            int r = min(rd[k], n_from - 1);      // clamp -> valid written slot
            slot[k] = map_slot(r, f1, f2, f3);
            float4 p = from[slot[k]];
            n2px[k] = -2.0f * p.x;
            n2py[k] = -2.0f * p.y;
            p2[k]   = p.z;
            m[k]    = BIGF;
        }
        for (int j = 0; j < cpad; j += 4) {      // quad-unroll, sentinel-padded
            float4 q0 = buf[j];                  // uniform addr -> LDS broadcast
            float4 q1 = buf[j + 1];
            float4 q2 = buf[j + 2];
            float4 q3 = buf[j + 3];
#pragma unroll
            for (int k = 0; k < RROWS; ++k) {
                float t0 = fmaf(q0.y, n2py[k], fmaf(q0.x, n2px[k], q0.z));
                float u1 = fmaf(q1.y, n2py[k], fmaf(q1.x, n2px[k], q1.z));
                m[k] = fminf(m[k], fminf(t0, u1));   // -> v_min3_f32
                float u2 = fmaf(q2.y, n2py[k], fmaf(q2.x, n2px[k], q2.z));
                float u3 = fmaf(q3.y, n2py[k], fmaf(q3.x, n2px[k], q3.z));
                m[k] = fminf(m[k], fminf(u2, u3));
            }
        }
#pragma unroll
        for (int k = 0; k < RROWS; ++k) {
            if (rd[k] < n_from) {
                float d2 = fmaxf(m[k] + p2[k], 0.0f);
                atomicMin(&minarr[combo * HW_ + slot[k]], __float_as_uint(d2));
            }
        }
    }
}

// One 1024-thread block per batch; both directions reduced concurrently
// (tid<512 -> dir0, else dir1). Iterates segments directly (slot-indexed).
__global__ void reduce_out_kernel(const int* __restrict__ segcounts,
                                  const unsigned int* __restrict__ minarr,
                                  float* __restrict__ out) {
    int b = blockIdx.x;
    int tid = threadIdx.x;
    int d = tid >> 9;                            // 0 or 1
    int t = tid & 511;
    int combo = b * 2 + d;

    float acc = 0.0f;
    for (int s = 0; s < NSEG; ++s) {
        int c = segcounts[combo * 4 + s];
        const unsigned int* ma = minarr + combo * HW_ + s * SEGCAP;
        for (int r = t; r < c; r += 512)
            acc += sqrtf(fmaxf(__uint_as_float(ma[r]), EPS_));
    }
#pragma unroll
    for (int o = 32; o >= 1; o >>= 1) acc += __shfl_down(acc, o);

    __shared__ float wsum[16];                   // waves 0-7 dir0, 8-15 dir1
    if ((tid & 63) == 0) wsum[tid >> 6] = acc;
    __syncthreads();
    if (tid == 0) {
        float s0 = 0.0f, s1 = 0.0f;
#pragma unroll
        for (int w = 0; w < 8; ++w)  s0 += wsum[w];
#pragma unroll
        for (int w = 8; w < 16; ++w) s1 += wsum[w];
        int n0 = 0, n1 = 0;
#pragma unroll
        for (int s = 0; s < NSEG; ++s) {
            n0 += segcounts[(b * 2) * 4 + s];
            n1 += segcounts[(b * 2 + 1) * 4 + s];
        }
        out[b] = (n0 > 0 && n1 > 0)
                 ? s0 / (float)n0 + s1 / (float)n1
                 : 1.0e6f;
    }
}

extern "C" void kernel_launch(void* const* d_in, const int* in_sizes, int n_in,
                              void* d_out, int out_size, void* d_ws, size_t ws_size,
                              hipStream_t stream) {
    const float* in1 = (const float*)d_in[0];
    const float* in2 = (const float*)d_in[1];
    float* out = (float*)d_out;
    char* ws = (char*)d_ws;
    int* segcounts = (int*)ws;
    float4* pts = (float4*)(ws + 256);
    unsigned int* minarr = (unsigned int*)(ws + 256 + (size_t)8 * HW_ * sizeof(float4));

    hipLaunchKernelGGL(compact_kernel, dim3(NSEG, 8), dim3(1024), 0, stream,
                       in1, in2, segcounts, pts, (uint4*)minarr);
    hipLaunchKernelGGL(dist_kernel, dim3(NCHUNK, 8), dim3(NTHR), 0, stream,
                       segcounts, pts, minarr);
    hipLaunchKernelGGL(reduce_out_kernel, dim3(B_), dim3(1024), 0, stream,
                       segcounts, minarr, out);
}

// Round 18
// 123.730 us; speedup vs baseline: 1.3183x; 1.3183x over previous
//
#include <hip/hip_runtime.h>
#include <math.h>

// Chamfer distance, B=4, H=W=128, HW=16384, threshold 0.1.
// ws layout:
//   [0,128)   int segcounts[8][4]   (plain stores, no memset needed)
//   [256, 256+8*HW*16)   float4 pts[8][HW]   segmented semi-dense:
//                        combo's seg s actives at [s*4096, s*4096+cnt)
//   [+2MB, +2MB+8*HW*4)  uint  minarr[8][HW] (d^2 bits, slot-indexed, atomicMin)

#define B_ 4
#define HW_ 16384
#define THRESH 0.1f
#define BIGF 1e30f
#define EPS_ 1e-12f

#define NTHR 512       // dist: 8 waves/block
#define RROWS 16       // rows/thread: keeps ds_read_b128 issue under VALU demand
#define NCHUNK 128     // to-split: 128 x 8 combos = 1024 blocks = 4/CU
#define MAXCHUNK 128   // ceil(HW/NCHUNK)
#define SEGCAP 4096    // elements per compaction segment
#define NSEG 4

// Atomic-free compaction: one block per (segment, combo). 1024 thr x 4 elems,
// float4 loads; in-block prefix scan (wave shfl + LDS); actives written dense
// within the segment; per-seg count = plain store. minarr init via uint4.
__global__ __launch_bounds__(1024)
void compact_kernel(const float* __restrict__ in1, const float* __restrict__ in2,
                    int* __restrict__ segcounts, float4* __restrict__ pts,
                    uint4* __restrict__ minarr4) {
    int seg = blockIdx.x, combo = blockIdx.y;
    int b = combo >> 1, s = combo & 1;
    int tid = threadIdx.x, lane = tid & 63, wid = tid >> 6;
    const float* in = s ? in2 : in1;
    int ibase = seg * SEGCAP + tid * 4;              // element index in image
    float4 v = ((const float4*)(in + b * HW_))[(unsigned)ibase >> 2];
    float w0 = v.x - THRESH, w1 = v.y - THRESH, w2 = v.z - THRESH, w3 = v.w - THRESH;
    int a0 = w0 > 0.f, a1 = w1 > 0.f, a2 = w2 > 0.f, a3 = w3 > 0.f;

    unsigned int bb = __float_as_uint(BIGF);
    minarr4[(unsigned)(combo * HW_ + ibase) >> 2] = make_uint4(bb, bb, bb, bb);

    int c = a0 + a1 + a2 + a3;
    int incl = c;
#pragma unroll
    for (int o = 1; o < 64; o <<= 1) {
        int x = __shfl_up(incl, o, 64);
        if (lane >= o) incl += x;
    }
    int wexcl = incl - c;
    __shared__ int wtot[16], wpre[17];
    if (lane == 63) wtot[wid] = incl;
    __syncthreads();
    if (tid == 0) {
        int run = 0;
#pragma unroll
        for (int ww = 0; ww < 16; ++ww) { wpre[ww] = run; run += wtot[ww]; }
        wpre[16] = run;
    }
    __syncthreads();
    int off = wpre[wid] + wexcl;
    float4* dst = pts + combo * HW_ + seg * SEGCAP;
    float wv[4] = {w0, w1, w2, w3};
    int   av[4] = {a0, a1, a2, a3};
#pragma unroll
    for (int u = 0; u < 4; ++u) {
        if (av[u]) {
            int i = ibase + u;
            float qx = (float)(i >> 7) * wv[u];
            float qy = (float)(i & 127) * wv[u];
            dst[off] = make_float4(qx, qy, qx * qx + qy * qy, 0.0f);
            ++off;
        }
    }
    if (tid == 0) segcounts[combo * 4 + seg] = wpre[16];
}

// dense index r in [0, n) -> segmented slot, given prefix offsets o1<=o2<=o3.
__device__ __forceinline__ int map_slot(int r, int o1, int o2, int o3) {
    int slot = r;
    slot = (r >= o1) ? r - o1 + SEGCAP     : slot;
    slot = (r >= o2) ? r - o2 + 2 * SEGCAP : slot;
    slot = (r >= o3) ? r - o3 + 3 * SEGCAP : slot;
    return slot;
}

// grid (NCHUNK, 8 combos), 512 threads. 1024 blocks = 4/CU; VGPR~60 allows
// 8 waves/SIMD natively -> 32 waves/CU WITHOUT a launch-bounds cap.
// (Round-16 lesson: __launch_bounds__(512,8) capped VGPR at 64 -> RROWS=16
// working set spilled to scratch -> 330 MB/dispatch HBM traffic, 2.4x slower.)
// Stage this block's to-chunk (<=128 float4 = 2KB, sentinel-padded to x4)
// into LDS once; each thread min-reduces RROWS=16 rows against it
// (dot form: 2 FMA + 0.5 min3 per pair, quad-unrolled, no remainder loop).
// Cross-chunk combine via uint atomicMin on d^2 bits (>=0 -> uint order ok).
__global__ __launch_bounds__(NTHR, 4)   // VGPR cap 128: natural alloc ~60, no spill
void dist_kernel(const int* __restrict__ segcounts,
                 const float4* __restrict__ pts,
                 unsigned int* __restrict__ minarr) {
    int chunk = blockIdx.x;
    int combo = blockIdx.y;
    int tid = threadIdx.x;
    int tc = combo ^ 1;
    int f1 = segcounts[combo * 4];
    int f2 = f1 + segcounts[combo * 4 + 1];
    int f3 = f2 + segcounts[combo * 4 + 2];
    int n_from = f3 + segcounts[combo * 4 + 3];
    int t1 = segcounts[tc * 4];
    int t2 = t1 + segcounts[tc * 4 + 1];
    int t3 = t2 + segcounts[tc * 4 + 2];
    int n_to = t3 + segcounts[tc * 4 + 3];
    if (n_from <= 0 || n_to <= 0) return;

    int len   = (n_to + NCHUNK - 1) / NCHUNK;
    int start = chunk * len;
    int end   = min(start + len, n_to);
    int clen  = end - start;
    if (clen <= 0) return;                       // block-uniform, before any sync
    int cpad  = (clen + 3) & ~3;                 // <= MAXCHUNK always

    const float4* __restrict__ to   = pts + tc * HW_;
    const float4* __restrict__ from = pts + combo * HW_;

    __shared__ float4 buf[MAXCHUNK];
    if (tid < clen)
        buf[tid] = to[map_slot(start + tid, t1, t2, t3)];
    else if (tid < cpad)
        buf[tid] = make_float4(0.0f, 0.0f, BIGF, 0.0f);  // sentinel: never the min
    __syncthreads();

    for (int rbase = 0; rbase < n_from; rbase += NTHR * RROWS) {
        int rd[RROWS], slot[RROWS];
        float n2px[RROWS], n2py[RROWS], p2[RROWS], m[RROWS];
#pragma unroll
        for (int k = 0; k < RROWS; ++k) {
            rd[k] = rbase + tid + k * NTHR;
            int r = min(rd[k], n_from - 1);      // clamp -> valid written slot
            slot[k] = map_slot(r, f1, f2, f3);
            float4 p = from[slot[k]];
            n2px[k] = -2.0f * p.x;
            n2py[k] = -2.0f * p.y;
            p2[k]   = p.z;
            m[k]    = BIGF;
        }
        for (int j = 0; j < cpad; j += 4) {      // quad-unroll, sentinel-padded
            float4 q0 = buf[j];                  // uniform addr -> LDS broadcast
            float4 q1 = buf[j + 1];
            float4 q2 = buf[j + 2];
            float4 q3 = buf[j + 3];
#pragma unroll
            for (int k = 0; k < RROWS; ++k) {
                float t0 = fmaf(q0.y, n2py[k], fmaf(q0.x, n2px[k], q0.z));
                float u1 = fmaf(q1.y, n2py[k], fmaf(q1.x, n2px[k], q1.z));
                m[k] = fminf(m[k], fminf(t0, u1));   // -> v_min3_f32
                float u2 = fmaf(q2.y, n2py[k], fmaf(q2.x, n2px[k], q2.z));
                float u3 = fmaf(q3.y, n2py[k], fmaf(q3.x, n2px[k], q3.z));
                m[k] = fminf(m[k], fminf(u2, u3));
            }
        }
#pragma unroll
        for (int k = 0; k < RROWS; ++k) {
            if (rd[k] < n_from) {
                float d2 = fmaxf(m[k] + p2[k], 0.0f);
                atomicMin(&minarr[combo * HW_ + slot[k]], __float_as_uint(d2));
            }
        }
    }
}

// One 1024-thread block per batch; both directions reduced concurrently
// (tid<512 -> dir0, else dir1). Iterates segments directly (slot-indexed).
__global__ void reduce_out_kernel(const int* __restrict__ segcounts,
                                  const unsigned int* __restrict__ minarr,
                                  float* __restrict__ out) {
    int b = blockIdx.x;
    int tid = threadIdx.x;
    int d = tid >> 9;                            // 0 or 1
    int t = tid & 511;
    int combo = b * 2 + d;

    float acc = 0.0f;
    for (int s = 0; s < NSEG; ++s) {
        int c = segcounts[combo * 4 + s];
        const unsigned int* ma = minarr + combo * HW_ + s * SEGCAP;
        for (int r = t; r < c; r += 512)
            acc += sqrtf(fmaxf(__uint_as_float(ma[r]), EPS_));
    }
#pragma unroll
    for (int o = 32; o >= 1; o >>= 1) acc += __shfl_down(acc, o);

    __shared__ float wsum[16];                   // waves 0-7 dir0, 8-15 dir1
    if ((tid & 63) == 0) wsum[tid >> 6] = acc;
    __syncthreads();
    if (tid == 0) {
        float s0 = 0.0f, s1 = 0.0f;
#pragma unroll
        for (int w = 0; w < 8; ++w)  s0 += wsum[w];
#pragma unroll
        for (int w = 8; w < 16; ++w) s1 += wsum[w];
        int n0 = 0, n1 = 0;
#pragma unroll
        for (int s = 0; s < NSEG; ++s) {
            n0 += segcounts[(b * 2) * 4 + s];
            n1 += segcounts[(b * 2 + 1) * 4 + s];
        }
        out[b] = (n0 > 0 && n1 > 0)
                 ? s0 / (float)n0 + s1 / (float)n1
                 : 1.0e6f;
    }
}

extern "C" void kernel_launch(void* const* d_in, const int* in_sizes, int n_in,
                              void* d_out, int out_size, void* d_ws, size_t ws_size,
                              hipStream_t stream) {
    const float* in1 = (const float*)d_in[0];
    const float* in2 = (const float*)d_in[1];
    float* out = (float*)d_out;
    char* ws = (char*)d_ws;
    int* segcounts = (int*)ws;
    float4* pts = (float4*)(ws + 256);
    unsigned int* minarr = (unsigned int*)(ws + 256 + (size_t)8 * HW_ * sizeof(float4));

    hipLaunchKernelGGL(compact_kernel, dim3(NSEG, 8), dim3(1024), 0, stream,
                       in1, in2, segcounts, pts, (uint4*)minarr);
    hipLaunchKernelGGL(dist_kernel, dim3(NCHUNK, 8), dim3(NTHR), 0, stream,
                       segcounts, pts, minarr);
    hipLaunchKernelGGL(reduce_out_kernel, dim3(B_), dim3(1024), 0, stream,
                       segcounts, minarr, out);
}

// Round 19
// 101.619 us; speedup vs baseline: 1.6052x; 1.2176x over previous
//
#include <hip/hip_runtime.h>
#include <math.h>

// Chamfer distance, B=4, H=W=128, HW=16384, threshold 0.1.
// ws layout:
//   [0,128)   int segcounts[8][4]   (plain stores, no memset needed)
//   [256, 256+8*HW*16)   float4 pts[8][HW]   segmented semi-dense:
//                        combo's seg s actives at [s*4096, s*4096+cnt)
//   [+2MB, +2MB+8*HW*4)  uint  minarr[8][HW] (d^2 bits, slot-indexed, atomicMin)

#define B_ 4
#define HW_ 16384
#define THRESH 0.1f
#define BIGF 1e30f
#define EPS_ 1e-12f

#define NTHR 512       // dist: 8 waves/block
#define RROWS 8        // rows/thread: working set ~48 VGPR fits in 60 -> no
                       // accvgpr spill churn (RROWS=16 needed ~100 regs; the
                       // ~2x VALU-issue inflation in r15/r18 matches unified-
                       // file AGPR spilling, invisible in FETCH/WRITE)
#define NCHUNK 64      // to-split: 64 x 8 combos = 512 blocks = 2/CU (r15-validated)
#define MAXCHUNK 256   // ceil(HW/NCHUNK); cpad <= 256 always
#define SEGCAP 4096    // elements per compaction segment
#define NSEG 4

// Atomic-free compaction: one block per (segment, combo). 1024 thr x 4 elems,
// float4 loads; in-block prefix scan (wave shfl + LDS); actives written dense
// within the segment; per-seg count = plain store. minarr init via uint4.
__global__ __launch_bounds__(1024)
void compact_kernel(const float* __restrict__ in1, const float* __restrict__ in2,
                    int* __restrict__ segcounts, float4* __restrict__ pts,
                    uint4* __restrict__ minarr4) {
    int seg = blockIdx.x, combo = blockIdx.y;
    int b = combo >> 1, s = combo & 1;
    int tid = threadIdx.x, lane = tid & 63, wid = tid >> 6;
    const float* in = s ? in2 : in1;
    int ibase = seg * SEGCAP + tid * 4;              // element index in image
    float4 v = ((const float4*)(in + b * HW_))[(unsigned)ibase >> 2];
    float w0 = v.x - THRESH, w1 = v.y - THRESH, w2 = v.z - THRESH, w3 = v.w - THRESH;
    int a0 = w0 > 0.f, a1 = w1 > 0.f, a2 = w2 > 0.f, a3 = w3 > 0.f;

    unsigned int bb = __float_as_uint(BIGF);
    minarr4[(unsigned)(combo * HW_ + ibase) >> 2] = make_uint4(bb, bb, bb, bb);

    int c = a0 + a1 + a2 + a3;
    int incl = c;
#pragma unroll
    for (int o = 1; o < 64; o <<= 1) {
        int x = __shfl_up(incl, o, 64);
        if (lane >= o) incl += x;
    }
    int wexcl = incl - c;
    __shared__ int wtot[16], wpre[17];
    if (lane == 63) wtot[wid] = incl;
    __syncthreads();
    if (tid == 0) {
        int run = 0;
#pragma unroll
        for (int ww = 0; ww < 16; ++ww) { wpre[ww] = run; run += wtot[ww]; }
        wpre[16] = run;
    }
    __syncthreads();
    int off = wpre[wid] + wexcl;
    float4* dst = pts + combo * HW_ + seg * SEGCAP;
    float wv[4] = {w0, w1, w2, w3};
    int   av[4] = {a0, a1, a2, a3};
#pragma unroll
    for (int u = 0; u < 4; ++u) {
        if (av[u]) {
            int i = ibase + u;
            float qx = (float)(i >> 7) * wv[u];
            float qy = (float)(i & 127) * wv[u];
            dst[off] = make_float4(qx, qy, qx * qx + qy * qy, 0.0f);
            ++off;
        }
    }
    if (tid == 0) segcounts[combo * 4 + seg] = wpre[16];
}

// dense index r in [0, n) -> segmented slot, given prefix offsets o1<=o2<=o3.
__device__ __forceinline__ int map_slot(int r, int o1, int o2, int o3) {
    int slot = r;
    slot = (r >= o1) ? r - o1 + SEGCAP     : slot;
    slot = (r >= o2) ? r - o2 + 2 * SEGCAP : slot;
    slot = (r >= o3) ? r - o3 + 3 * SEGCAP : slot;
    return slot;
}

// grid (NCHUNK=64, 8 combos), 512 threads = 2 blocks/CU. Stage this block's
// to-chunk (<=256 float4 = 4KB, sentinel-padded to x4) into LDS once; each
// thread min-reduces RROWS=8 rows against it (dot form: 2 FMA + 0.5 min3 per
// pair, quad-unrolled, no remainder). Cross-chunk combine via uint atomicMin
// on d^2 bits (>=0 -> uint order = float order).
__global__ __launch_bounds__(NTHR, 4)   // VGPR cap 128: natural alloc, no spill
void dist_kernel(const int* __restrict__ segcounts,
                 const float4* __restrict__ pts,
                 unsigned int* __restrict__ minarr) {
    int chunk = blockIdx.x;
    int combo = blockIdx.y;
    int tid = threadIdx.x;
    int tc = combo ^ 1;
    int f1 = segcounts[combo * 4];
    int f2 = f1 + segcounts[combo * 4 + 1];
    int f3 = f2 + segcounts[combo * 4 + 2];
    int n_from = f3 + segcounts[combo * 4 + 3];
    int t1 = segcounts[tc * 4];
    int t2 = t1 + segcounts[tc * 4 + 1];
    int t3 = t2 + segcounts[tc * 4 + 2];
    int n_to = t3 + segcounts[tc * 4 + 3];
    if (n_from <= 0 || n_to <= 0) return;

    int len   = (n_to + NCHUNK - 1) / NCHUNK;
    int start = chunk * len;
    int end   = min(start + len, n_to);
    int clen  = end - start;
    if (clen <= 0) return;                       // block-uniform, before any sync
    int cpad  = (clen + 3) & ~3;                 // <= MAXCHUNK always

    const float4* __restrict__ to   = pts + tc * HW_;
    const float4* __restrict__ from = pts + combo * HW_;

    __shared__ float4 buf[MAXCHUNK];
    if (tid < clen)
        buf[tid] = to[map_slot(start + tid, t1, t2, t3)];
    else if (tid < cpad)
        buf[tid] = make_float4(0.0f, 0.0f, BIGF, 0.0f);  // sentinel: never the min
    __syncthreads();

    for (int rbase = 0; rbase < n_from; rbase += NTHR * RROWS) {
        int rd[RROWS], slot[RROWS];
        float n2px[RROWS], n2py[RROWS], p2[RROWS], m[RROWS];
#pragma unroll
        for (int k = 0; k < RROWS; ++k) {
            rd[k] = rbase + tid + k * NTHR;
            int r = min(rd[k], n_from - 1);      // clamp -> valid written slot
            slot[k] = map_slot(r, f1, f2, f3);
            float4 p = from[slot[k]];
            n2px[k] = -2.0f * p.x;
            n2py[k] = -2.0f * p.y;
            p2[k]   = p.z;
            m[k]    = BIGF;
        }
        for (int j = 0; j < cpad; j += 4) {      // quad-unroll, sentinel-padded
            float4 q0 = buf[j];                  // uniform addr -> LDS broadcast
            float4 q1 = buf[j + 1];
            float4 q2 = buf[j + 2];
            float4 q3 = buf[j + 3];
#pragma unroll
            for (int k = 0; k < RROWS; ++k) {
                float t0 = fmaf(q0.y, n2py[k], fmaf(q0.x, n2px[k], q0.z));
                float u1 = fmaf(q1.y, n2py[k], fmaf(q1.x, n2px[k], q1.z));
                m[k] = fminf(m[k], fminf(t0, u1));   // -> v_min3_f32
                float u2 = fmaf(q2.y, n2py[k], fmaf(q2.x, n2px[k], q2.z));
                float u3 = fmaf(q3.y, n2py[k], fmaf(q3.x, n2px[k], q3.z));
                m[k] = fminf(m[k], fminf(u2, u3));
            }
        }
#pragma unroll
        for (int k = 0; k < RROWS; ++k) {
            if (rd[k] < n_from) {
                float d2 = fmaxf(m[k] + p2[k], 0.0f);
                atomicMin(&minarr[combo * HW_ + slot[k]], __float_as_uint(d2));
            }
        }
    }
}

// One 1024-thread block per batch; both directions reduced concurrently
// (tid<512 -> dir0, else dir1). Iterates segments directly (slot-indexed).
__global__ void reduce_out_kernel(const int* __restrict__ segcounts,
                                  const unsigned int* __restrict__ minarr,
                                  float* __restrict__ out) {
    int b = blockIdx.x;
    int tid = threadIdx.x;
    int d = tid >> 9;                            // 0 or 1
    int t = tid & 511;
    int combo = b * 2 + d;

    float acc = 0.0f;
    for (int s = 0; s < NSEG; ++s) {
        int c = segcounts[combo * 4 + s];
        const unsigned int* ma = minarr + combo * HW_ + s * SEGCAP;
        for (int r = t; r < c; r += 512)
            acc += sqrtf(fmaxf(__uint_as_float(ma[r]), EPS_));
    }
#pragma unroll
    for (int o = 32; o >= 1; o >>= 1) acc += __shfl_down(acc, o);

    __shared__ float wsum[16];                   // waves 0-7 dir0, 8-15 dir1
    if ((tid & 63) == 0) wsum[tid >> 6] = acc;
    __syncthreads();
    if (tid == 0) {
        float s0 = 0.0f, s1 = 0.0f;
#pragma unroll
        for (int w = 0; w < 8; ++w)  s0 += wsum[w];
#pragma unroll
        for (int w = 8; w < 16; ++w) s1 += wsum[w];
        int n0 = 0, n1 = 0;
#pragma unroll
        for (int s = 0; s < NSEG; ++s) {
            n0 += segcounts[(b * 2) * 4 + s];
            n1 += segcounts[(b * 2 + 1) * 4 + s];
        }
        out[b] = (n0 > 0 && n1 > 0)
                 ? s0 / (float)n0 + s1 / (float)n1
                 : 1.0e6f;
    }
}

extern "C" void kernel_launch(void* const* d_in, const int* in_sizes, int n_in,
                              void* d_out, int out_size, void* d_ws, size_t ws_size,
                              hipStream_t stream) {
    const float* in1 = (const float*)d_in[0];
    const float* in2 = (const float*)d_in[1];
    float* out = (float*)d_out;
    char* ws = (char*)d_ws;
    int* segcounts = (int*)ws;
    float4* pts = (float4*)(ws + 256);
    unsigned int* minarr = (unsigned int*)(ws + 256 + (size_t)8 * HW_ * sizeof(float4));

    hipLaunchKernelGGL(compact_kernel, dim3(NSEG, 8), dim3(1024), 0, stream,
                       in1, in2, segcounts, pts, (uint4*)minarr);
    hipLaunchKernelGGL(dist_kernel, dim3(NCHUNK, 8), dim3(NTHR), 0, stream,
                       segcounts, pts, minarr);
    hipLaunchKernelGGL(reduce_out_kernel, dim3(B_), dim3(1024), 0, stream,
                       segcounts, minarr, out);
}